// Round 5
// baseline (176.635 us; speedup 1.0000x reference)
//
#include <hip/hip_runtime.h>
#include <hip/hip_cooperative_groups.h>
#include <math.h>

namespace cg = cooperative_groups;

constexpr int Bn = 8, Cn = 512, Sn = 256, Mn = 200, Ln = 100;

// workspace layout (in floats)
constexpr size_t OFF_V    = 0;                                 // [B][C][S]
constexpr size_t OFF_Z    = OFF_V   + (size_t)Bn*Cn*Sn;        // [B][M][S]
constexpr size_t OFF_INV  = OFF_Z   + (size_t)Bn*Mn*Sn;        // [B][M]
constexpr size_t OFF_ZW   = OFF_INV + (size_t)Bn*Mn;           // [B][M]
constexpr size_t OFF_ZPW  = OFF_ZW  + (size_t)Bn*Mn;           // [B][M]
constexpr size_t OFF_WSUM = OFF_ZPW + (size_t)Bn*Mn;           // [S]

// LDS structs (union max = PszS 12,288 B; +red4 64 B -> 12.4 KB/block;
// even with a 64KB-per-CU occupancy model: floor(64K/12.4K)=5 >= 4 blocks/CU)
struct PoolS { float lds[256][9]; };
struct PszS  { float pc[4][256]; float As[4][512]; };
struct GS    { float zl[4][256]; float invl[200]; float zwl[200]; };
struct OutS  { float vl[4][256]; float zpl[200]; float t2l[8][104];
               float resl[2][4]; float vsl[4]; };
union ShU { PoolS p; PszS z; GS g; OutS o; };

// ---------- vectorized block reductions (4 waves / 256 threads) ----------
__device__ __forceinline__ float4 blk_max_f4(float4 x, float4* red) {
  #pragma unroll
  for (int o = 32; o; o >>= 1) {
    x.x = fmaxf(x.x, __shfl_xor(x.x, o));
    x.y = fmaxf(x.y, __shfl_xor(x.y, o));
    x.z = fmaxf(x.z, __shfl_xor(x.z, o));
    x.w = fmaxf(x.w, __shfl_xor(x.w, o));
  }
  __syncthreads();
  if ((threadIdx.x & 63) == 0) red[threadIdx.x >> 6] = x;
  __syncthreads();
  float4 r = red[0];
  #pragma unroll
  for (int w = 1; w < 4; ++w) {
    r.x = fmaxf(r.x, red[w].x); r.y = fmaxf(r.y, red[w].y);
    r.z = fmaxf(r.z, red[w].z); r.w = fmaxf(r.w, red[w].w);
  }
  return r;
}
__device__ __forceinline__ float4 blk_sum_f4(float4 x, float4* red) {
  #pragma unroll
  for (int o = 32; o; o >>= 1) {
    x.x += __shfl_xor(x.x, o); x.y += __shfl_xor(x.y, o);
    x.z += __shfl_xor(x.z, o); x.w += __shfl_xor(x.w, o);
  }
  __syncthreads();
  if ((threadIdx.x & 63) == 0) red[threadIdx.x >> 6] = x;
  __syncthreads();
  float4 r = red[0];
  #pragma unroll
  for (int w = 1; w < 4; ++w) {
    r.x += red[w].x; r.y += red[w].y; r.z += red[w].z; r.w += red[w].w;
  }
  return r;
}

// ===== phase 0: 8x8 block-mean pool (4 planes/block, two-pass LDS transpose)
__device__ void dev_pool(const float* __restrict__ x, const float* __restrict__ ow,
                         float* __restrict__ ws, PoolS& sh, int bl, int t) {
  #pragma unroll 1
  for (int rp = 0; rp < 4; ++rp) {
    int bc = bl + rp * 1024;                  // plane 0..4095
    const float* plane = x + (size_t)bc * 16384;
    float part[16];
    #pragma unroll
    for (int i = 0; i < 16; ++i) {
      float4 f = *(const float4*)(plane + i * 1024 + t * 4);
      part[i] = f.x + f.y + f.z + f.w;
    }
    int i = t >> 4, jj = t & 15;
    float s = 0.f;
    __syncthreads();                          // protect prev-iter reads
    #pragma unroll
    for (int q = 0; q < 8; ++q) sh.lds[t][q] = part[q];
    __syncthreads();
    if (i < 8) {
      #pragma unroll
      for (int r = 0; r < 8; ++r)
        s += sh.lds[32 * r + 2 * jj][i] + sh.lds[32 * r + 2 * jj + 1][i];
    }
    __syncthreads();
    #pragma unroll
    for (int q = 0; q < 8; ++q) sh.lds[t][q] = part[8 + q];
    __syncthreads();
    if (i >= 8) {
      #pragma unroll
      for (int r = 0; r < 8; ++r)
        s += sh.lds[32 * r + 2 * jj][i - 8] + sh.lds[32 * r + 2 * jj + 1][i - 8];
    }
    ws[OFF_V + (size_t)bc * 256 + t] = s * (1.0f / 64.0f);
  }
  if (bl == 0) {                              // wsum[s] = sum_t out_w[s,t]
    const float* row = ow + (size_t)t * Sn;
    float s = 0.f;
    for (int j = 0; j < Sn; j += 4) {
      float4 f = *(const float4*)(row + j);
      s += f.x + f.y + f.z + f.w;
    }
    ws[OFF_WSUM + t] = s;
  }
}

// ===== phase 1: t1 = v.psi -> softmax_c -> A(LDS) -> z = A.v, ||z||, z.wsum
// 400 units: (b, m-group of 4)
__device__ void dev_psz(const float* __restrict__ psi, float* __restrict__ ws,
                        PszS& sh, float4* red4, int bl, int t) {
  if (bl >= 400) return;
  int b = bl / 50, g = bl % 50, m0 = g * 4;
  const float* v = ws + OFF_V + (size_t)b * Cn * Sn;
  for (int e = t; e < 4 * 256; e += 256) {
    int mm = e >> 8, s = e & 255;
    int m = m0 + mm, k = m / Ln, d = m % Ln;
    sh.pc[mm][s] = psi[(size_t)k * Sn * Ln + (size_t)s * Ln + d];
  }
  __syncthreads();
  // thread t owns channels c = t and c = t+256
  float acc[2][4];
  #pragma unroll
  for (int mm = 0; mm < 4; ++mm) { acc[0][mm] = 0.f; acc[1][mm] = 0.f; }
  const float* vp0 = v + (size_t)t * Sn;
  const float* vp1 = v + (size_t)(t + 256) * Sn;
  for (int s = 0; s < Sn; s += 4) {
    float4 v0 = *(const float4*)(vp0 + s);
    float4 v1 = *(const float4*)(vp1 + s);
    #pragma unroll
    for (int mm = 0; mm < 4; ++mm) {
      float4 p = *(const float4*)&sh.pc[mm][s];
      acc[0][mm] += v0.x * p.x + v0.y * p.y + v0.z * p.z + v0.w * p.w;
      acc[1][mm] += v1.x * p.x + v1.y * p.y + v1.z * p.z + v1.w * p.w;
    }
  }
  float4 a = make_float4(fmaxf(acc[0][0], acc[1][0]), fmaxf(acc[0][1], acc[1][1]),
                         fmaxf(acc[0][2], acc[1][2]), fmaxf(acc[0][3], acc[1][3]));
  float4 mx = blk_max_f4(a, red4);
  float e00 = expf(acc[0][0] - mx.x), e10 = expf(acc[1][0] - mx.x);
  float e01 = expf(acc[0][1] - mx.y), e11 = expf(acc[1][1] - mx.y);
  float e02 = expf(acc[0][2] - mx.z), e12 = expf(acc[1][2] - mx.z);
  float e03 = expf(acc[0][3] - mx.w), e13 = expf(acc[1][3] - mx.w);
  float4 se = blk_sum_f4(make_float4(e00 + e10, e01 + e11, e02 + e12, e03 + e13),
                         red4);
  sh.As[0][t] = e00 / se.x; sh.As[0][t + 256] = e10 / se.x;
  sh.As[1][t] = e01 / se.y; sh.As[1][t + 256] = e11 / se.y;
  sh.As[2][t] = e02 / se.z; sh.As[2][t + 256] = e12 / se.z;
  sh.As[3][t] = e03 / se.w; sh.As[3][t + 256] = e13 / se.w;
  __syncthreads();
  // z[m, s=t] = sum_c As[m][c] * v[c][t]  (coalesced v reads, As broadcast)
  float zv[4] = {0, 0, 0, 0};
  for (int c = 0; c < Cn; c += 4) {
    float w0 = v[(size_t)(c + 0) * Sn + t];
    float w1 = v[(size_t)(c + 1) * Sn + t];
    float w2 = v[(size_t)(c + 2) * Sn + t];
    float w3 = v[(size_t)(c + 3) * Sn + t];
    #pragma unroll
    for (int mm = 0; mm < 4; ++mm) {
      float4 aa = *(const float4*)&sh.As[mm][c];
      zv[mm] += aa.x * w0 + aa.y * w1 + aa.z * w2 + aa.w * w3;
    }
  }
  float wsv = ws[OFF_WSUM + t];
  float* zo = ws + OFF_Z + ((size_t)b * Mn + m0) * Sn;
  #pragma unroll
  for (int mm = 0; mm < 4; ++mm) zo[(size_t)mm * Sn + t] = zv[mm];
  float4 n2 = blk_sum_f4(make_float4(zv[0]*zv[0], zv[1]*zv[1],
                                     zv[2]*zv[2], zv[3]*zv[3]), red4);
  float4 zw = blk_sum_f4(make_float4(zv[0]*wsv, zv[1]*wsv,
                                     zv[2]*wsv, zv[3]*wsv), red4);
  if (t == 0) {
    float* inv = ws + OFF_INV + (size_t)b * Mn + m0;
    float* zwp = ws + OFF_ZW  + (size_t)b * Mn + m0;
    inv[0] = 1.0f / (sqrtf(n2.x) + 1e-6f); zwp[0] = zw.x;
    inv[1] = 1.0f / (sqrtf(n2.y) + 1e-6f); zwp[1] = zw.y;
    inv[2] = 1.0f / (sqrtf(n2.z) + 1e-6f); zwp[2] = zw.z;
    inv[3] = 1.0f / (sqrtf(n2.w) + 1e-6f); zwp[3] = zw.w;
  }
}

// ===== phase 2: G = softmax_n(zn.zn); zp_w[m] = sum_n G[m,n] zw[n]
// 400 units: (b, m-group of 4)
__device__ void dev_g(float* __restrict__ ws, GS& sh, float4* red4, int bl, int t) {
  if (bl >= 400) return;
  int b = bl / 50, g2 = bl % 50, m0 = g2 * 4;
  const float* z = ws + OFF_Z + (size_t)b * Mn * Sn;
  #pragma unroll
  for (int mm = 0; mm < 4; ++mm)
    sh.zl[mm][t] = z[(size_t)(m0 + mm) * Sn + t];
  if (t < Mn) {
    sh.invl[t] = ws[OFF_INV + (size_t)b * Mn + t];
    sh.zwl[t]  = ws[OFF_ZW  + (size_t)b * Mn + t];
  }
  __syncthreads();
  bool act = t < Mn;
  float dot[4] = {0, 0, 0, 0};
  if (act) {
    const float* zr = z + (size_t)t * Sn;
    for (int s = 0; s < Sn; s += 4) {
      float4 zz = *(const float4*)(zr + s);
      #pragma unroll
      for (int mm = 0; mm < 4; ++mm) {
        float4 zl4 = *(const float4*)&sh.zl[mm][s];
        dot[mm] += zz.x * zl4.x + zz.y * zl4.y + zz.z * zl4.z + zz.w * zl4.w;
      }
    }
  }
  float4 val;
  val.x = act ? dot[0] * sh.invl[m0 + 0] * sh.invl[t] : -1e30f;
  val.y = act ? dot[1] * sh.invl[m0 + 1] * sh.invl[t] : -1e30f;
  val.z = act ? dot[2] * sh.invl[m0 + 2] * sh.invl[t] : -1e30f;
  val.w = act ? dot[3] * sh.invl[m0 + 3] * sh.invl[t] : -1e30f;
  float4 mx = blk_max_f4(val, red4);
  float4 e;
  e.x = act ? expf(val.x - mx.x) : 0.f;
  e.y = act ? expf(val.y - mx.y) : 0.f;
  e.z = act ? expf(val.z - mx.z) : 0.f;
  e.w = act ? expf(val.w - mx.w) : 0.f;
  float4 se = blk_sum_f4(e, red4);
  float zwn = act ? sh.zwl[t] : 0.f;
  float4 sez = blk_sum_f4(make_float4(e.x*zwn, e.y*zwn, e.z*zwn, e.w*zwn), red4);
  if (t == 0) {
    float* zp = ws + OFF_ZPW + (size_t)b * Mn + m0;
    zp[0] = sez.x / se.x; zp[1] = sez.y / se.y;
    zp[2] = sez.z / se.z; zp[3] = sez.w / se.w;
  }
}

// ===== phase 3: t2 = v.phi, softmax_d, dot zp_w, + vsum, sigmoid
// 1024 units: (b, c-group of 4)
__device__ void dev_out(const float* __restrict__ phi, float* __restrict__ out,
                        float* __restrict__ ws, OutS& sh, int bl, int t) {
  int b = bl >> 7, cgrp = bl & 127, c0 = cgrp * 4;
  const float* v = ws + OFF_V + ((size_t)b * Cn + c0) * Sn;
  #pragma unroll
  for (int cc = 0; cc < 4; ++cc) sh.vl[cc][t] = v[(size_t)cc * Sn + t];
  if (t < Mn) sh.zpl[t] = ws[OFF_ZPW + (size_t)b * Mn + t];
  __syncthreads();
  int k = t >> 7, d = t & 127;
  int dd = d < Ln ? d : Ln - 1;
  const float* pp = phi + (size_t)k * Sn * Ln + dd;
  float acc[4] = {0, 0, 0, 0};
  for (int s = 0; s < Sn; s += 4) {
    float p0 = pp[(size_t)(s + 0) * Ln];
    float p1 = pp[(size_t)(s + 1) * Ln];
    float p2 = pp[(size_t)(s + 2) * Ln];
    float p3 = pp[(size_t)(s + 3) * Ln];
    #pragma unroll
    for (int cc = 0; cc < 4; ++cc) {
      float4 vv = *(const float4*)&sh.vl[cc][s];
      acc[cc] += vv.x * p0 + vv.y * p1 + vv.z * p2 + vv.w * p3;
    }
  }
  if (d < Ln) {
    #pragma unroll
    for (int cc = 0; cc < 4; ++cc) sh.t2l[k * 4 + cc][d] = acc[cc];
  }
  __syncthreads();
  int gg = t >> 5, l = t & 31;
  int k2 = gg >> 2, cc2 = gg & 3;
  float mx = -1e30f;
  for (int dq = l; dq < Ln; dq += 32) mx = fmaxf(mx, sh.t2l[gg][dq]);
  #pragma unroll
  for (int o = 16; o; o >>= 1) mx = fmaxf(mx, __shfl_xor(mx, o));
  float se = 0.f, sez = 0.f;
  for (int dq = l; dq < Ln; dq += 32) {
    float e = expf(sh.t2l[gg][dq] - mx);
    se += e;
    sez += e * sh.zpl[k2 * Ln + dq];
  }
  #pragma unroll
  for (int o = 16; o; o >>= 1) { se += __shfl_xor(se, o); sez += __shfl_xor(sez, o); }
  float vs = 0.f;
  if (k2 == 0) {
    for (int i2 = 0; i2 < 8; ++i2) vs += sh.vl[cc2][i2 * 32 + l];
    #pragma unroll
    for (int o = 16; o; o >>= 1) vs += __shfl_xor(vs, o);
    if (l == 0) sh.vsl[cc2] = vs;
  }
  if (l == 0) sh.resl[k2][cc2] = sez / se;
  __syncthreads();
  if (t < 4) {
    float f = (sh.vsl[t] + sh.resl[0][t] + sh.resl[1][t]) * (1.0f / 256.0f);
    out[(size_t)b * Cn + c0 + t] = 1.0f / (1.0f + expf(-f));
  }
}

// ===== cooperative single-kernel path
__global__ void __launch_bounds__(256, 4)
k_all(const float* __restrict__ x, const float* __restrict__ psi,
      const float* __restrict__ phi, const float* __restrict__ ow,
      float* __restrict__ out, float* __restrict__ ws) {
  cg::grid_group grid = cg::this_grid();
  __shared__ ShU sh;
  __shared__ float4 red4[4];
  int t = threadIdx.x, bl = blockIdx.x;
  dev_pool(x, ow, ws, sh.p, bl, t);
  grid.sync();
  dev_psz(psi, ws, sh.z, red4, bl, t);
  grid.sync();
  dev_g(ws, sh.g, red4, bl, t);
  grid.sync();
  dev_out(phi, out, ws, sh.o, bl, t);
}

// ===== fallback multi-kernel path (same device code, 4 dispatches)
__global__ void __launch_bounds__(256) k_pool_f(const float* __restrict__ x,
                                                const float* __restrict__ ow,
                                                float* __restrict__ ws) {
  __shared__ PoolS sh;
  dev_pool(x, ow, ws, sh, blockIdx.x, threadIdx.x);
}
__global__ void __launch_bounds__(256) k_psz_f(const float* __restrict__ psi,
                                               float* __restrict__ ws) {
  __shared__ PszS sh; __shared__ float4 red4[4];
  dev_psz(psi, ws, sh, red4, blockIdx.x, threadIdx.x);
}
__global__ void __launch_bounds__(256) k_g_f(float* __restrict__ ws) {
  __shared__ GS sh; __shared__ float4 red4[4];
  dev_g(ws, sh, red4, blockIdx.x, threadIdx.x);
}
__global__ void __launch_bounds__(256) k_out_f(const float* __restrict__ phi,
                                               float* __restrict__ out,
                                               float* __restrict__ ws) {
  __shared__ OutS sh;
  dev_out(phi, out, ws, sh, blockIdx.x, threadIdx.x);
}

extern "C" void kernel_launch(void* const* d_in, const int* in_sizes, int n_in,
                              void* d_out, int out_size, void* d_ws, size_t ws_size,
                              hipStream_t stream) {
  const float* x   = (const float*)d_in[0];
  const float* psi = (const float*)d_in[1];
  const float* phi = (const float*)d_in[2];
  const float* ow  = (const float*)d_in[3];
  float* out = (float*)d_out;
  float* ws  = (float*)d_ws;

  int maxBlk = 0;
  hipError_t qerr = hipOccupancyMaxActiveBlocksPerMultiprocessor(
      &maxBlk, (const void*)k_all, 256, 0);
  bool coop = (qerr == hipSuccess && maxBlk >= 4);

  if (coop) {
    void* args[] = {(void*)&x, (void*)&psi, (void*)&phi, (void*)&ow,
                    (void*)&out, (void*)&ws};
    hipError_t lerr = hipLaunchCooperativeKernel(
        (void*)k_all, dim3(1024), dim3(256), args, 0, stream);
    if (lerr == hipSuccess) return;
  }
  // fallback: 4 regular dispatches
  hipLaunchKernelGGL(k_pool_f, dim3(1024),  dim3(256), 0, stream, x, ow, ws);
  hipLaunchKernelGGL(k_psz_f,  dim3(400),   dim3(256), 0, stream, psi, ws);
  hipLaunchKernelGGL(k_g_f,    dim3(400),   dim3(256), 0, stream, ws);
  hipLaunchKernelGGL(k_out_f,  dim3(1024),  dim3(256), 0, stream, phi, out, ws);
}